// Round 12
// baseline (54.627 us; speedup 1.0000x reference)
//
#include <hip/hip_runtime.h>

typedef __attribute__((ext_vector_type(2))) float f32x2;

#define W 4096
#define H 4096
#define NT 256
#define NW 4
#define WCOLS 128                // columns per wave (64 lanes x 2)
#define SR 32                    // output rows per wave strip
#define GROUP 4                  // rows staged per pipeline step
#define NSTAGE (SR + 14)         // 46 staged rows contribute
#define NG 12                    // 12 groups of 4 (48 slots, last 2 guarded)
#define LW 144                   // staged row: float f <-> col cw-8+f
#define RAD 7
#define PEND 18                  // 15 + GROUP - 1

__device__ __forceinline__ void gl_lds16(float* lds, const float* g) {
    __builtin_amdgcn_global_load_lds(
        (const __attribute__((address_space(1))) void*)g,
        (__attribute__((address_space(3))) void*)lds, 16, 0, 0);
}
__device__ __forceinline__ void gl_lds4(float* lds, const float* g) {
    __builtin_amdgcn_global_load_lds(
        (const __attribute__((address_space(1))) void*)g,
        (__attribute__((address_space(3))) void*)lds, 4, 0, 0);
}

__global__ __launch_bounds__(NT, 4) void multibox_kernel(
    const float* __restrict__ x, const float* __restrict__ base,
    float* __restrict__ out)
{
    // per-wave private triple-buffered staging: NO __syncthreads anywhere
    __shared__ float buf[NW][3][GROUP][LW];   // 27,648 B

    const int t  = threadIdx.x;
    const int w  = t >> 6;                     // wave id
    const int l  = t & 63;                     // lane
    const int cw = blockIdx.x * WCOLS;         // wave's column panel
    const int i0 = (blockIdx.y * NW + w) * SR; // wave's private row strip

    const float w3  = 1.f/(7.f*9.f);
    const float w5  = 1.f/(7.f*25.f);
    const float w7  = 1.f/(7.f*49.f);
    const float w9  = 1.f/(7.f*81.f);
    const float w11 = 1.f/(7.f*121.f);
    const float w13 = 1.f/(7.f*169.f);
    const float w15 = 1.f/(7.f*225.f);

    // Exact-edge 3-op DMA per row (float f <-> col cw-8+f):
    //  L: f=0..63    4B/lane, per-lane clamp -> exact edge replicate
    //  M: f=64..127  16B/lane, lanes 0..15, cols cw+56..cw+119 always in-range
    //  R: f=128..143 4B/lane, lanes 0..15, per-lane clamp -> exact replicate
    const int colL = min(max(cw -  8 +     l, 0), W - 1);
    const int colM =         cw + 56 + 4 * l;
    const int colR = min(    cw + 120 +    l,     W - 1);

    // wave stages its 4 rows of group g into slot b: 12 DMA ops
    auto stage = [&](int g, int b) {
#pragma unroll
        for (int rr = 0; rr < GROUP; ++rr) {
            const int rc = min(max(i0 - RAD + g * GROUP + rr, 0), H - 1);
            const float* rp = x + (size_t)rc * W;
            float* lb = &buf[w][b][rr][0];
            gl_lds4(lb, rp + colL);
            if (l < 16) {
                gl_lds16(lb +  64, rp + colM);
                gl_lds4 (lb + 128, rp + colR);
            }
        }
    };

    // Pnd[p] accumulates output row (i0 + 4g - 14 + p) before group g.
    // rr / p compile-time (inner unrolls); g stays RUNTIME (rounds 4/7 lesson).
    f32x2 Pnd[PEND];
#pragma unroll
    for (int q = 0; q < PEND; ++q) Pnd[q] = f32x2{0.f, 0.f};

    auto compute_group = [&](int b, int g) {
#pragma unroll
        for (int rr = 0; rr < GROUP; ++rr) {
            if (g * GROUP + rr < NSTAGE) {
                const float* p = &buf[w][b][rr][2 * l];
                f32x2 q2[9];
#pragma unroll
                for (int i = 0; i < 9; ++i) q2[i] = *(const f32x2*)(p + 2 * i);

                auto PR = [&](int a) -> f32x2 {
                    if ((a & 1) == 0) return q2[a / 2];
                    f32x2 r;
                    r.x = q2[a / 2].y;
                    r.y = q2[a / 2 + 1].x;
                    return r;
                };

                f32x2 s3  = PR(7) + PR(8) + PR(9);
                f32x2 s5  = s3  + PR(6) + PR(10);
                f32x2 s7  = s5  + PR(5) + PR(11);
                f32x2 s9  = s7  + PR(4) + PR(12);
                f32x2 s11 = s9  + PR(3) + PR(13);
                f32x2 s13 = s11 + PR(2) + PR(14);
                f32x2 s15 = s13 + PR(1) + PR(15);

                f32x2 c7 = f32x2{w15, w15} * s15;
                f32x2 c6 = c7 + f32x2{w13, w13} * s13;
                f32x2 c5 = c6 + f32x2{w11, w11} * s11;
                f32x2 c4 = c5 + f32x2{w9 , w9 } * s9;
                f32x2 c3 = c4 + f32x2{w7 , w7 } * s7;
                f32x2 c2 = c3 + f32x2{w5 , w5 } * s5;
                f32x2 c1 = c2 + f32x2{w3 , w3 } * s3;

                Pnd[rr +  0] += c7; Pnd[rr +  1] += c6; Pnd[rr +  2] += c5;
                Pnd[rr +  3] += c4; Pnd[rr +  4] += c3; Pnd[rr +  5] += c2;
                Pnd[rr +  6] += c1; Pnd[rr +  7] += c1; Pnd[rr +  8] += c1;
                Pnd[rr +  9] += c2; Pnd[rr + 10] += c3; Pnd[rr + 11] += c4;
                Pnd[rr + 12] += c5; Pnd[rr + 13] += c6; Pnd[rr + 14] += c7;
            }
        }

        // emit completed rows: o_ofs = 4g - 14 + p (base loaded at use; its
        // dependent wait is compiler-tracked and per-wave)
#pragma unroll
        for (int p = 0; p < GROUP; ++p) {
            const int o_ofs = 4 * g - 14 + p;
            if (o_ofs >= 0 && o_ofs < SR) {
                const size_t bi = (size_t)(i0 + o_ofs) * W + cw + 2 * l;
                f32x2 bm = *(const f32x2*)(base + bi);
                f32x2 ov = Pnd[p] * bm;
                *(f32x2*)(out + bi) = ov;
            }
        }

        // shift window by GROUP (static indices)
#pragma unroll
        for (int p = 0; p < PEND - GROUP; ++p) Pnd[p] = Pnd[p + GROUP];
#pragma unroll
        for (int p = PEND - GROUP; p < PEND; ++p) Pnd[p] = f32x2{0.f, 0.f};
    };

    // prologue: 2 groups in flight; wait g0 (12 ops of stage(1) may remain)
    stage(0, 0);
    stage(1, 1);
    asm volatile("s_waitcnt vmcnt(12)" ::: "memory");
    __builtin_amdgcn_sched_barrier(0);

    // Per-wave pipeline, no barriers. Bottom-of-iter wait guarantees
    // stage(g+1) retired before next compute. vmcnt N = ops issued after
    // stage(g+1): emits E(g)={0,0,0,4,8,...,8,4}; smaller N = safe over-wait.
    //   g<=3: 12 | g==4: 24 | 5<=g<=NG-3: 28 | g==NG-2: 16
    int b = 0;
#pragma clang loop unroll(disable)
    for (int g = 0; g < NG; ++g) {
        int b2 = b + 2; if (b2 >= 3) b2 -= 3;
        if (g + 2 < NG) stage(g + 2, b2);   // issue 12 DMA ops early
        __builtin_amdgcn_sched_barrier(0);  // pin: DMA before compute
        compute_group(b, g);                // ds_read + VALU + base/out VMEM
        if (g + 1 < NG) {
            if (g <= 3)          asm volatile("s_waitcnt vmcnt(12)" ::: "memory");
            else if (g == 4)     asm volatile("s_waitcnt vmcnt(24)" ::: "memory");
            else if (g == NG - 2)asm volatile("s_waitcnt vmcnt(16)" ::: "memory");
            else                 asm volatile("s_waitcnt vmcnt(28)" ::: "memory");
            __builtin_amdgcn_sched_barrier(0);
        }
        ++b; if (b >= 3) b = 0;
    }
}

extern "C" void kernel_launch(void* const* d_in, const int* in_sizes, int n_in,
                              void* d_out, int out_size, void* d_ws, size_t ws_size,
                              hipStream_t stream) {
    const float* x    = (const float*)d_in[0];
    const float* base = (const float*)d_in[1];
    float* out        = (float*)d_out;

    dim3 grid(W / WCOLS, H / (NW * SR));   // (32, 32) = 1024 blocks, 4096 waves
    multibox_kernel<<<grid, dim3(NT), 0, stream>>>(x, base, out);
}